// Round 1
// baseline (33.906 us; speedup 1.0000x reference)
//
#include <hip/hip_runtime.h>
#include <hip/hip_bf16.h>

// permute_multi_embedding:
//   v0: (B, 512) f32, v1: (B, 768) f32, v2: (B, 256) f32, B = 16384
//   out0 (B, 640) = v0[:,0:128] | v1[:,0:256] | v2[:,0:256]
//   out1 (B, 896) = v0[:,128:384] | v1[:,256:768] | v0[:,384:512]
// d_out = out0 flat (B*640) then out1 flat (B*896).
// All offsets/lengths are multiples of 4 floats -> float4 everywhere.
// Row strides in float4 units: v0=128, v1=192, v2=64, out0=160, out1=224.

#define B_ROWS 16384

__global__ __launch_bounds__(384) void PermuteMultiEmbedding_68582037782900_kernel(
    const float4* __restrict__ v0,
    const float4* __restrict__ v1,
    const float4* __restrict__ v2,
    float4* __restrict__ out0,
    float4* __restrict__ out1)
{
    const int row = blockIdx.x;
    const int t = threadIdx.x;  // 0..383, one float4 each

    if (t < 160) {
        // ---- out0: 160 float4 per row ----
        const int c = t;
        float4 val;
        if (c < 32) {                 // v0[:, 0:128)   -> f4 cols 0..31
            val = v0[row * 128 + c];
        } else if (c < 96) {          // v1[:, 0:256)   -> f4 cols 0..63
            val = v1[row * 192 + (c - 32)];
        } else {                      // v2[:, 0:256)   -> f4 cols 0..63
            val = v2[row * 64 + (c - 96)];
        }
        out0[row * 160 + c] = val;
    } else {
        // ---- out1: 224 float4 per row ----
        const int c = t - 160;
        float4 val;
        if (c < 64) {                 // v0[:, 128:384) -> f4 cols 32..95
            val = v0[row * 128 + 32 + c];
        } else if (c < 192) {         // v1[:, 256:768) -> f4 cols 64..191
            val = v1[row * 192 + c];  // 64 + (c - 64)
        } else {                      // v0[:, 384:512) -> f4 cols 96..127
            val = v0[row * 128 + 96 + (c - 192)];
        }
        out1[row * 224 + c] = val;
    }
}

extern "C" void kernel_launch(void* const* d_in, const int* in_sizes, int n_in,
                              void* d_out, int out_size, void* d_ws, size_t ws_size,
                              hipStream_t stream) {
    const float4* v0 = (const float4*)d_in[0];
    const float4* v1 = (const float4*)d_in[1];
    const float4* v2 = (const float4*)d_in[2];
    float4* out0 = (float4*)d_out;
    float4* out1 = out0 + (size_t)B_ROWS * 160;  // out0 is B*640 floats = B*160 float4

    PermuteMultiEmbedding_68582037782900_kernel<<<B_ROWS, 384, 0, stream>>>(
        v0, v1, v2, out0, out1);
}

// Round 2
// 33.519 us; speedup vs baseline: 1.0115x; 1.0115x over previous
//
#include <hip/hip_runtime.h>
#include <hip/hip_bf16.h>

// permute_multi_embedding:
//   v0: (B, 512) f32, v1: (B, 768) f32, v2: (B, 256) f32, B = 16384
//   out0 (B, 640) = v0[:,0:128] | v1[:,0:256] | v2[:,0:256]
//   out1 (B, 896) = v0[:,128:384] | v1[:,256:768] | v0[:,384:512]
// d_out = out0 flat (B*640) then out1 flat (B*896).
// All offsets/lengths are multiples of 4 floats -> float4 everywhere.
// Row strides in float4 units: v0=128, v1=192, v2=64, out0=160, out1=224.
//
// R2 change: nontemporal stores for the outputs (written once, never
// re-read) so the 100.7 MB input set stays Infinity-Cache-resident across
// graph replays -> reads become L3 hits, writes stream to HBM.

#define B_ROWS 16384

typedef float v4f __attribute__((ext_vector_type(4)));

__global__ __launch_bounds__(384) void PermuteMultiEmbedding_68582037782900_kernel(
    const v4f* __restrict__ v0,
    const v4f* __restrict__ v1,
    const v4f* __restrict__ v2,
    v4f* __restrict__ out0,
    v4f* __restrict__ out1)
{
    const int row = blockIdx.x;
    const int t = threadIdx.x;  // 0..383, one float4 each

    if (t < 160) {
        // ---- out0: 160 float4 per row ----
        const int c = t;
        v4f val;
        if (c < 32) {                 // v0[:, 0:128)   -> f4 cols 0..31
            val = v0[row * 128 + c];
        } else if (c < 96) {          // v1[:, 0:256)   -> f4 cols 0..63
            val = v1[row * 192 + (c - 32)];
        } else {                      // v2[:, 0:256)   -> f4 cols 0..63
            val = v2[row * 64 + (c - 96)];
        }
        __builtin_nontemporal_store(val, &out0[row * 160 + c]);
    } else {
        // ---- out1: 224 float4 per row ----
        const int c = t - 160;
        v4f val;
        if (c < 64) {                 // v0[:, 128:384) -> f4 cols 32..95
            val = v0[row * 128 + 32 + c];
        } else if (c < 192) {         // v1[:, 256:768) -> f4 cols 64..191
            val = v1[row * 192 + c];  // 64 + (c - 64)
        } else {                      // v0[:, 384:512) -> f4 cols 96..127
            val = v0[row * 128 + 96 + (c - 192)];
        }
        __builtin_nontemporal_store(val, &out1[row * 224 + c]);
    }
}

extern "C" void kernel_launch(void* const* d_in, const int* in_sizes, int n_in,
                              void* d_out, int out_size, void* d_ws, size_t ws_size,
                              hipStream_t stream) {
    const v4f* v0 = (const v4f*)d_in[0];
    const v4f* v1 = (const v4f*)d_in[1];
    const v4f* v2 = (const v4f*)d_in[2];
    v4f* out0 = (v4f*)d_out;
    v4f* out1 = out0 + (size_t)B_ROWS * 160;  // out0 is B*640 floats = B*160 float4

    PermuteMultiEmbedding_68582037782900_kernel<<<B_ROWS, 384, 0, stream>>>(
        v0, v1, v2, out0, out1);
}